// Round 1
// 388.201 us; speedup vs baseline: 1.1395x; 1.1395x over previous
//
#include <hip/hip_runtime.h>
#include <stdint.h>

// Triangle multiplicative update (outgoing), N=512, CZ=CH=128.
// Stage A (proj_fuse): one pass over z computes all 4 projections
//   (ag,ap,bg,bp); a = mask*sigmoid(zWag+bag)*(zWap+bap), likewise b;
//   stored bf16 as planes [c][pos] in d_ws.
//   v2: weights hoisted to VGPRs once per block (64 VGPR/wave slice),
//   8 waves = 4 proj x 2 channel-halves, 16 position-tiles per block
//   -> weight L2 traffic cut 16x (was the 7% MfmaUtil bottleneck).
// Stage B (tri_gemm): out[c,i,j] = sum_k a[i,k,c]*b[j,k,c] -> 128 GEMMs.
//   v2: 1D grid + c-locality XCD swizzle: all 16 tiles of channel c land
//   on one XCD (linear id mod 8) so A_c/B_c are HBM-fetched once.

#define NDIM 512
#define CZ   128
#define CH   128
#define NPOS (NDIM * NDIM)  // 262144
#define NTILE 16            // position tiles per proj_fuse block
#define POSB  (NTILE * 32)  // 512 positions per block

typedef __attribute__((ext_vector_type(8))) __bf16 bf16x8;
typedef __attribute__((ext_vector_type(4))) float  f32x4;

__device__ __forceinline__ unsigned short f2bf(float f) {
  unsigned int u = __builtin_bit_cast(unsigned int, f);
  unsigned int r = (u + 0x7fffu + ((u >> 16) & 1u)) >> 16;  // RNE
  return (unsigned short)r;
}
__device__ __forceinline__ float bf2f_lo(unsigned int u) {
  return __builtin_bit_cast(float, u << 16);
}
__device__ __forceinline__ float bf2f_hi(unsigned int u) {
  return __builtin_bit_cast(float, u & 0xffff0000u);
}

// ---------------------------------------------------------------- kernel 0
// fp32 -> bf16 weights, layout [proj][c][k], proj: 0=ag,1=ap,2=bg,3=bp.
__global__ __launch_bounds__(256) void conv_weights(
    const float* __restrict__ wag, const float* __restrict__ wap,
    const float* __restrict__ wbg, const float* __restrict__ wbp,
    unsigned short* __restrict__ wbf) {
  int idx = blockIdx.x * 256 + threadIdx.x;  // 0..65535
  int proj = idx >> 14;
  int rem  = idx & 16383;
  const float* src = (proj == 0) ? wag : (proj == 1) ? wap : (proj == 2) ? wbg : wbp;
  wbf[idx] = f2bf(src[rem]);
}

// ---------------------------------------------------------------- kernel A
// Block: 512 threads = 8 waves. Wave w handles projection (w&3), channel
// half (w>>2). Its weight slice [64 ch][128 cz] bf16 lives in 64 VGPRs,
// loaded ONCE, reused across 16 tiles of 32 positions (512 pos/block).
// Per tile: stage z->LDS bf16, MFMA (acc 2x4), acc->LDS bf16, fused
// sigmoid epilogue with coalesced [c][pos] plane stores.
__global__ __launch_bounds__(512, 4) void proj_fuse(
    const float* __restrict__ z,            // [NPOS][CZ]
    const float* __restrict__ mask,         // [NPOS]
    const unsigned short* __restrict__ wbf, // [4][CH][CZ] bf16
    const float* __restrict__ bias_ag, const float* __restrict__ bias_ap,
    const float* __restrict__ bias_bg, const float* __restrict__ bias_bp,
    unsigned short* __restrict__ a_ws,      // [CH][NPOS] bf16
    unsigned short* __restrict__ b_ws) {
  __shared__ unsigned short zbuf[32 * 136];      // 8.7 KB, padded stride
  __shared__ unsigned short accb[4 * 128 * 36];  // 36.9 KB, [proj][c][pos] bf16

  const int t    = threadIdx.x;
  const int lane = t & 63;
  const int w    = t >> 6;   // 0..7
  const int proj = w & 3;    // projection id
  const int half = w >> 2;   // channel half (0: ch 0..63, 1: ch 64..127)
  const int base = blockIdx.x * POSB;

  const int ml    = lane & 15;
  const int q     = lane >> 4;
  const int koffl = q * 8;

  // ---- hoist this wave's weight slice into VGPRs (64 VGPR), once.
  // wfrag[ks][ni] covers ch = half*64 + ni*16 + ml, k = ks*32 + koffl..+7
  bf16x8 wfrag[4][4];
#pragma unroll
  for (int ks = 0; ks < 4; ++ks)
#pragma unroll
    for (int ni = 0; ni < 4; ++ni)
      wfrag[ks][ni] = *(const bf16x8*)&wbf[((size_t)proj * CH + half * 64 + ni * 16 + ml) * CZ + ks * 32 + koffl];

  // ---- hoist epilogue biases (thread's channels are fixed across tiles)
  const int pc = t & 7;    // pos chunk (4 positions)
  const int cb = t >> 3;   // 0..63 channel base
  float bga[2], bpa[2], bgb[2], bpb[2];
#pragma unroll
  for (int it = 0; it < 2; ++it) {
    bga[it] = bias_ag[it * 64 + cb];
    bpa[it] = bias_ap[it * 64 + cb];
    bgb[it] = bias_bg[it * 64 + cb];
    bpb[it] = bias_bp[it * 64 + cb];
  }

#pragma unroll 1
  for (int tt = 0; tt < NTILE; ++tt) {
    const int m0 = base + tt * 32;

    // ---- stage z tile [32 pos][128 cz] fp32 -> bf16 (512 threads, 2 f4 each)
#pragma unroll
    for (int it = 0; it < 2; ++it) {
      const int id  = it * 512 + t;   // 0..1023
      const int row = id >> 5;        // 0..31
      const int c4  = id & 31;
      const float4 v = *(const float4*)(z + (size_t)(m0 + row) * CZ + c4 * 4);
      unsigned int lo = (unsigned int)f2bf(v.x) | ((unsigned int)f2bf(v.y) << 16);
      unsigned int hi = (unsigned int)f2bf(v.z) | ((unsigned int)f2bf(v.w) << 16);
      *(uint2*)&zbuf[row * 136 + c4 * 4] = make_uint2(lo, hi);
    }
    __syncthreads();

    // ---- MFMA: wave -> its projection/half over [32 pos][64 ch]
    f32x4 acc[2][4];
#pragma unroll
    for (int mi = 0; mi < 2; ++mi)
#pragma unroll
      for (int ni = 0; ni < 4; ++ni) acc[mi][ni] = (f32x4){0.f, 0.f, 0.f, 0.f};

#pragma unroll
    for (int ks = 0; ks < 4; ++ks) {
      bf16x8 af0 = *(const bf16x8*)&zbuf[(ml)      * 136 + ks * 32 + koffl];
      bf16x8 af1 = *(const bf16x8*)&zbuf[(ml + 16) * 136 + ks * 32 + koffl];
#pragma unroll
      for (int ni = 0; ni < 4; ++ni) {
        acc[0][ni] = __builtin_amdgcn_mfma_f32_16x16x32_bf16(af0, wfrag[ks][ni], acc[0][ni], 0, 0, 0);
        acc[1][ni] = __builtin_amdgcn_mfma_f32_16x16x32_bf16(af1, wfrag[ks][ni], acc[1][ni], 0, 0, 0);
      }
    }

    // ---- write acc (bf16) to accb[proj][c][pos]; col=ml -> channel,
    //      row = q*4+r (+16*mi) -> position. 8B stores, stride 36.
#pragma unroll
    for (int mi = 0; mi < 2; ++mi)
#pragma unroll
      for (int ni = 0; ni < 4; ++ni) {
        const int c    = half * 64 + ni * 16 + ml;
        const int pos0 = mi * 16 + q * 4;
        unsigned int lo = (unsigned int)f2bf(acc[mi][ni][0]) |
                          ((unsigned int)f2bf(acc[mi][ni][1]) << 16);
        unsigned int hi = (unsigned int)f2bf(acc[mi][ni][2]) |
                          ((unsigned int)f2bf(acc[mi][ni][3]) << 16);
        *(uint2*)&accb[((size_t)proj * CH + c) * 36 + pos0] = make_uint2(lo, hi);
      }
    __syncthreads();

    // ---- epilogue: all 512 threads; out = mask*sigmoid(g+bg)*(p+bp)
    const float4 mv = *(const float4*)(mask + m0 + pc * 4);
    const float mr[4] = {mv.x, mv.y, mv.z, mv.w};
#pragma unroll
    for (int pair = 0; pair < 2; ++pair) {
      const float* bgp = pair ? bgb : bga;
      const float* bpp = pair ? bpb : bpa;
      unsigned short* plane = pair ? b_ws : a_ws;
      const int pg = pair * 2, pp = pg + 1;
#pragma unroll
      for (int it = 0; it < 2; ++it) {
        const int ch = it * 64 + cb;
        uint2 gv = *(const uint2*)&accb[((size_t)pg * CH + ch) * 36 + pc * 4];
        uint2 pv = *(const uint2*)&accb[((size_t)pp * CH + ch) * 36 + pc * 4];
        const float bg = bgp[it];
        const float bp = bpp[it];
        float g[4] = {bf2f_lo(gv.x) + bg, bf2f_hi(gv.x) + bg,
                      bf2f_lo(gv.y) + bg, bf2f_hi(gv.y) + bg};
        float p[4] = {bf2f_lo(pv.x) + bp, bf2f_hi(pv.x) + bp,
                      bf2f_lo(pv.y) + bp, bf2f_hi(pv.y) + bp};
        unsigned short h[4];
#pragma unroll
        for (int r = 0; r < 4; ++r) {
          float s = 1.0f / (1.0f + __expf(-g[r]));
          h[r] = f2bf(mr[r] * s * p[r]);
        }
        *(uint2*)(plane + (size_t)ch * NPOS + m0 + pc * 4) =
            make_uint2((unsigned int)h[0] | ((unsigned int)h[1] << 16),
                       (unsigned int)h[2] | ((unsigned int)h[3] << 16));
      }
    }
    __syncthreads();  // protect zbuf/accb before next tile
  }
}

// ---------------------------------------------------------------- kernel B
// Per-channel GEMM out[c] = A_c * B_c^T, bf16 [512][512].
// 128x128 tile, BK=64, global_load_lds width-16, XOR-swizzled LDS chunks.
// 1D grid, c-locality XCD swizzle: linear id = slot*8 + xcd (round-robin
// dispatch puts id%8 on one XCD); all 16 tiles of a channel share an XCD
// so A_c/B_c (1 MB) are HBM-fetched once into that XCD's L2.
__global__ __launch_bounds__(256, 3) void tri_gemm(
    const unsigned short* __restrict__ a_ws,
    const unsigned short* __restrict__ b_ws,
    float* __restrict__ out) {
  __shared__ unsigned short sA[128 * 64];
  __shared__ unsigned short sB[128 * 64];

  const int t = threadIdx.x, lane = t & 63, wave = t >> 6;
  const int wm = wave >> 1, wn = wave & 1;

  const int L    = blockIdx.x;     // 0..2047
  const int xcd  = L & 7;
  const int slot = L >> 3;         // 0..255
  const int c    = xcd * 16 + (slot >> 4);
  const int tile = slot & 15;      // 16 tiles of channel c, schedule-adjacent
  const int ti   = tile >> 2, tj = tile & 3;
  const int i0 = ti * 128, j0 = tj * 128;

  const unsigned short* Ap = a_ws + (size_t)c * NPOS + (size_t)i0 * NDIM;
  const unsigned short* Bp = b_ws + (size_t)c * NPOS + (size_t)j0 * NDIM;

  f32x4 acc[4][4];
#pragma unroll
  for (int mi = 0; mi < 4; ++mi)
#pragma unroll
    for (int ni = 0; ni < 4; ++ni) acc[mi][ni] = (f32x4){0.f, 0.f, 0.f, 0.f};

  const int srow8  = t >> 3;  // row within a 32-row staging group
  const int schunk = t & 7;   // physical 16B chunk within row
  const int mrow = wm * 64 + (lane & 15);
  const int nrow = wn * 64 + (lane & 15);

  for (int kk = 0; kk < 8; ++kk) {
    const int k0 = kk * 64;  // shorts
#pragma unroll
    for (int i = 0; i < 4; ++i) {
      const int row = i * 32 + srow8;
      const int kcs = schunk ^ (row & 7);  // swizzled source chunk
      __builtin_amdgcn_global_load_lds(
          (const __attribute__((address_space(1))) unsigned int*)(Ap + (size_t)row * NDIM + k0 + kcs * 8),
          (__attribute__((address_space(3))) unsigned int*)&sA[(i * 256 + t) * 8], 16, 0, 0);
      __builtin_amdgcn_global_load_lds(
          (const __attribute__((address_space(1))) unsigned int*)(Bp + (size_t)row * NDIM + k0 + kcs * 8),
          (__attribute__((address_space(3))) unsigned int*)&sB[(i * 256 + t) * 8], 16, 0, 0);
    }
    __syncthreads();

#pragma unroll
    for (int ksub = 0; ksub < 2; ++ksub) {
      const int kc = ksub * 4 + (lane >> 4);  // logical 16B chunk 0..7
      bf16x8 af[4], bfr[4];
#pragma unroll
      for (int mi = 0; mi < 4; ++mi) {
        const int r = mrow + mi * 16;
        af[mi] = *(const bf16x8*)&sA[r * 64 + ((kc ^ (r & 7)) << 3)];
      }
#pragma unroll
      for (int ni = 0; ni < 4; ++ni) {
        const int r = nrow + ni * 16;
        bfr[ni] = *(const bf16x8*)&sB[r * 64 + ((kc ^ (r & 7)) << 3)];
      }
#pragma unroll
      for (int mi = 0; mi < 4; ++mi)
#pragma unroll
        for (int ni = 0; ni < 4; ++ni)
          acc[mi][ni] = __builtin_amdgcn_mfma_f32_16x16x32_bf16(af[mi], bfr[ni], acc[mi][ni], 0, 0, 0);
    }
    __syncthreads();
  }

  float* O = out + (size_t)c * NPOS + (size_t)i0 * NDIM + j0;
#pragma unroll
  for (int mi = 0; mi < 4; ++mi)
#pragma unroll
    for (int r = 0; r < 4; ++r) {
      const int m = wm * 64 + mi * 16 + (lane >> 4) * 4 + r;
#pragma unroll
      for (int ni = 0; ni < 4; ++ni) {
        const int n = wn * 64 + ni * 16 + (lane & 15);
        O[(size_t)m * NDIM + n] = acc[mi][ni][r];
      }
    }
}

// ---------------------------------------------------------------- launcher
extern "C" void kernel_launch(void* const* d_in, const int* in_sizes, int n_in,
                              void* d_out, int out_size, void* d_ws, size_t ws_size,
                              hipStream_t stream) {
  const float* z    = (const float*)d_in[0];
  const float* mask = (const float*)d_in[1];
  const float* wag  = (const float*)d_in[2];
  const float* bag  = (const float*)d_in[3];
  const float* wap  = (const float*)d_in[4];
  const float* bap  = (const float*)d_in[5];
  const float* wbg  = (const float*)d_in[6];
  const float* bbg  = (const float*)d_in[7];
  const float* wbp  = (const float*)d_in[8];
  const float* bbp  = (const float*)d_in[9];
  float* out = (float*)d_out;

  unsigned short* wbf  = (unsigned short*)d_ws;
  unsigned short* a_ws = (unsigned short*)((char*)d_ws + 131072);
  unsigned short* b_ws = (unsigned short*)((char*)d_ws + 131072 + (size_t)CH * NPOS * 2);

  conv_weights<<<dim3(256), dim3(256), 0, stream>>>(wag, wap, wbg, wbp, wbf);
  proj_fuse<<<dim3(NPOS / POSB), dim3(512), 0, stream>>>(
      z, mask, wbf, bag, bap, bbg, bbp, a_ws, b_ws);
  tri_gemm<<<dim3(2048), dim3(256), 0, stream>>>(a_ws, b_ws, out);
}

// Round 3
// 382.879 us; speedup vs baseline: 1.1553x; 1.0139x over previous
//
#include <hip/hip_runtime.h>
#include <stdint.h>

// Triangle multiplicative update (outgoing), N=512, CZ=CH=128.
// Stage A (proj_fuse v3): grid (512,2); y picks pair (a|b). 256-thread
//   blocks, wave = channel quarter, computes BOTH gate and lin projections
//   with weights truly VGPR-resident (64 VGPR, lb(256,3) cap 170 -- v2's
//   lb(512,4) cap 128 forced rematerialization, VGPR_Count=64 proved it).
//   In-register sigmoid combine, direct plane stores, zbuf double-buffered
//   -> 1 barrier/tile, no accb LDS round-trip, no bank conflicts.
// Stage B (tri_gemm v3): 128 per-channel GEMMs, 128x128 tile, BK=64,
//   now double-buffered LDS (2-phase pipeline): issue next K-tile's
//   global_load_lds BEFORE computing current -> load latency hidden under
//   ds_read+MFMA; one barrier per K-step. c-locality XCD swizzle kept.
// (Round-2 resubmit: round-1 bench died on container acquisition, no
//  counters returned; source audit found no hang/fault candidate.)

#define NDIM 512
#define CZ   128
#define CH   128
#define NPOS (NDIM * NDIM)  // 262144
#define NTILE 16            // position tiles per proj_fuse block
#define POSB  (NTILE * 32)  // 512 positions per block

typedef __attribute__((ext_vector_type(8))) __bf16 bf16x8;
typedef __attribute__((ext_vector_type(4))) float  f32x4;

__device__ __forceinline__ unsigned short f2bf(float f) {
  unsigned int u = __builtin_bit_cast(unsigned int, f);
  unsigned int r = (u + 0x7fffu + ((u >> 16) & 1u)) >> 16;  // RNE
  return (unsigned short)r;
}

// ---------------------------------------------------------------- kernel 0
// fp32 -> bf16 weights, layout [proj][c][k], proj: 0=ag,1=ap,2=bg,3=bp.
__global__ __launch_bounds__(256) void conv_weights(
    const float* __restrict__ wag, const float* __restrict__ wap,
    const float* __restrict__ wbg, const float* __restrict__ wbp,
    unsigned short* __restrict__ wbf) {
  int idx = blockIdx.x * 256 + threadIdx.x;  // 0..65535
  int proj = idx >> 14;
  int rem  = idx & 16383;
  const float* src = (proj == 0) ? wag : (proj == 1) ? wap : (proj == 2) ? wbg : wbp;
  wbf[idx] = f2bf(src[rem]);
}

// ---------------------------------------------------------------- kernel A
// Block: 256 threads = 4 waves, handles pair (blockIdx.y: 0=a, 1=b) over
// 512 positions (16 tiles x 32). Wave w owns channel quarter w (32 ch) and
// computes gate+lin for it; weights resident in 64 VGPR. Epilogue fully
// in-register; 8B stores to [c][pos] planes (L2 merges to full lines).
__global__ __launch_bounds__(256, 3) void proj_fuse(
    const float* __restrict__ z,            // [NPOS][CZ]
    const float* __restrict__ mask,         // [NPOS]
    const unsigned short* __restrict__ wbf, // [4][CH][CZ] bf16
    const float* __restrict__ bias_ag, const float* __restrict__ bias_ap,
    const float* __restrict__ bias_bg, const float* __restrict__ bias_bp,
    unsigned short* __restrict__ a_ws,      // [CH][NPOS] bf16
    unsigned short* __restrict__ b_ws) {
  __shared__ unsigned short zbuf[2][32 * 136];  // 2 x 8.7 KB, padded stride

  const int t    = threadIdx.x;
  const int lane = t & 63;
  const int w    = t >> 6;          // 0..3 = channel quarter
  const int pair = blockIdx.y;      // 0=a, 1=b
  const int base = blockIdx.x * POSB;

  const int ml    = lane & 15;
  const int q     = lane >> 4;
  const int koffl = q * 8;
  const int pg = pair * 2, pp = pg + 1;

  // ---- weights resident in VGPRs: gate + lin for 32 channels (64 VGPR)
  bf16x8 wg[4][2], wp[4][2];
#pragma unroll
  for (int ks = 0; ks < 4; ++ks)
#pragma unroll
    for (int ni = 0; ni < 2; ++ni) {
      const int c = w * 32 + ni * 16 + ml;
      wg[ks][ni] = *(const bf16x8*)&wbf[((size_t)pg * CH + c) * CZ + ks * 32 + koffl];
      wp[ks][ni] = *(const bf16x8*)&wbf[((size_t)pp * CH + c) * CZ + ks * 32 + koffl];
    }

  // ---- biases for this lane's channels
  const float* bgp = pair ? bias_bg : bias_ag;
  const float* bpp = pair ? bias_bp : bias_ap;
  float bg[2], bp[2];
#pragma unroll
  for (int ni = 0; ni < 2; ++ni) {
    bg[ni] = bgp[w * 32 + ni * 16 + ml];
    bp[ni] = bpp[w * 32 + ni * 16 + ml];
  }
  unsigned short* plane = pair ? b_ws : a_ws;

  // ---- stage tile tt (32 pos x 128 cz, fp32 -> bf16) into zbuf[b]
  auto STAGE = [&](int b, int tt) {
    const int m0s = base + tt * 32;
#pragma unroll
    for (int it = 0; it < 4; ++it) {
      const int id  = it * 256 + t;   // 0..1023
      const int row = id >> 5;        // 0..31
      const int c4  = id & 31;
      const float4 v = *(const float4*)(z + (size_t)(m0s + row) * CZ + c4 * 4);
      unsigned int lo = (unsigned int)f2bf(v.x) | ((unsigned int)f2bf(v.y) << 16);
      unsigned int hi = (unsigned int)f2bf(v.z) | ((unsigned int)f2bf(v.w) << 16);
      *(uint2*)&zbuf[b][row * 136 + c4 * 4] = make_uint2(lo, hi);
    }
  };

  STAGE(0, 0);
  __syncthreads();

#pragma unroll 1
  for (int tt = 0; tt < NTILE; ++tt) {
    const int m0 = base + tt * 32;
    const int cb = tt & 1;
    if (tt + 1 < NTILE) STAGE(cb ^ 1, tt + 1);  // prefetch next tile

    // ---- MFMA: acc[mi][ni] for gate and lin over [32 pos][32 ch]
    f32x4 ag_[2][2], ap_[2][2];
#pragma unroll
    for (int mi = 0; mi < 2; ++mi)
#pragma unroll
      for (int ni = 0; ni < 2; ++ni) {
        ag_[mi][ni] = (f32x4){0.f, 0.f, 0.f, 0.f};
        ap_[mi][ni] = (f32x4){0.f, 0.f, 0.f, 0.f};
      }

#pragma unroll
    for (int ks = 0; ks < 4; ++ks) {
      bf16x8 af0 = *(const bf16x8*)&zbuf[cb][(ml)      * 136 + ks * 32 + koffl];
      bf16x8 af1 = *(const bf16x8*)&zbuf[cb][(ml + 16) * 136 + ks * 32 + koffl];
#pragma unroll
      for (int ni = 0; ni < 2; ++ni) {
        ag_[0][ni] = __builtin_amdgcn_mfma_f32_16x16x32_bf16(af0, wg[ks][ni], ag_[0][ni], 0, 0, 0);
        ag_[1][ni] = __builtin_amdgcn_mfma_f32_16x16x32_bf16(af1, wg[ks][ni], ag_[1][ni], 0, 0, 0);
        ap_[0][ni] = __builtin_amdgcn_mfma_f32_16x16x32_bf16(af0, wp[ks][ni], ap_[0][ni], 0, 0, 0);
        ap_[1][ni] = __builtin_amdgcn_mfma_f32_16x16x32_bf16(af1, wp[ks][ni], ap_[1][ni], 0, 0, 0);
      }
    }

    // ---- in-register epilogue: out = mask*sigmoid(g+bg)*(p+bp)
    // C-layout (validated in v1/v2): channel = ni*16+ml, pos = mi*16+q*4+r
#pragma unroll
    for (int mi = 0; mi < 2; ++mi) {
      const int pos0 = mi * 16 + q * 4;
      const float4 mv = *(const float4*)(mask + m0 + pos0);
      const float mr[4] = {mv.x, mv.y, mv.z, mv.w};
#pragma unroll
      for (int ni = 0; ni < 2; ++ni) {
        const int c = w * 32 + ni * 16 + ml;
        unsigned short h[4];
#pragma unroll
        for (int r = 0; r < 4; ++r) {
          const float g = ag_[mi][ni][r] + bg[ni];
          const float p = ap_[mi][ni][r] + bp[ni];
          const float s = 1.0f / (1.0f + __expf(-g));
          h[r] = f2bf(mr[r] * s * p);
        }
        *(uint2*)(plane + (size_t)c * NPOS + m0 + pos0) =
            make_uint2((unsigned int)h[0] | ((unsigned int)h[1] << 16),
                       (unsigned int)h[2] | ((unsigned int)h[3] << 16));
      }
    }
    __syncthreads();  // zbuf[cb] free for the prefetch of tt+2
  }
}

// ---------------------------------------------------------------- kernel B
// Per-channel GEMM out[c] = A_c * B_c^T, bf16 [512][512].
// 128x128 tile, BK=64, double-buffered LDS, global_load_lds width-16,
// XOR-swizzled chunks. 2-phase pipeline: next tile's loads issued before
// current tile's compute; one barrier per K-step (syncthreads drains vmcnt).
__global__ __launch_bounds__(256, 2) void tri_gemm(
    const unsigned short* __restrict__ a_ws,
    const unsigned short* __restrict__ b_ws,
    float* __restrict__ out) {
  __shared__ unsigned short sA[2][128 * 64];  // 32 KB
  __shared__ unsigned short sB[2][128 * 64];  // 32 KB

  const int t = threadIdx.x, lane = t & 63, wave = t >> 6;
  const int wm = wave >> 1, wn = wave & 1;

  const int L    = blockIdx.x;     // 0..2047
  const int xcd  = L & 7;
  const int slot = L >> 3;         // 0..255
  const int c    = xcd * 16 + (slot >> 4);
  const int tile = slot & 15;      // 16 tiles of channel c, schedule-adjacent
  const int ti   = tile >> 2, tj = tile & 3;
  const int i0 = ti * 128, j0 = tj * 128;

  const unsigned short* Ap = a_ws + (size_t)c * NPOS + (size_t)i0 * NDIM;
  const unsigned short* Bp = b_ws + (size_t)c * NPOS + (size_t)j0 * NDIM;

  f32x4 acc[4][4];
#pragma unroll
  for (int mi = 0; mi < 4; ++mi)
#pragma unroll
    for (int ni = 0; ni < 4; ++ni) acc[mi][ni] = (f32x4){0.f, 0.f, 0.f, 0.f};

  const int srow8  = t >> 3;  // row within a 32-row staging group
  const int schunk = t & 7;   // physical 16B chunk within row
  const int mrow = wm * 64 + (lane & 15);
  const int nrow = wn * 64 + (lane & 15);

  auto STAGE = [&](int b, int kk) {
    const int k0 = kk * 64;  // shorts
#pragma unroll
    for (int i = 0; i < 4; ++i) {
      const int row = i * 32 + srow8;
      const int kcs = schunk ^ (row & 7);  // swizzled source chunk
      __builtin_amdgcn_global_load_lds(
          (const __attribute__((address_space(1))) unsigned int*)(Ap + (size_t)row * NDIM + k0 + kcs * 8),
          (__attribute__((address_space(3))) unsigned int*)&sA[b][(i * 256 + t) * 8], 16, 0, 0);
      __builtin_amdgcn_global_load_lds(
          (const __attribute__((address_space(1))) unsigned int*)(Bp + (size_t)row * NDIM + k0 + kcs * 8),
          (__attribute__((address_space(3))) unsigned int*)&sB[b][(i * 256 + t) * 8], 16, 0, 0);
    }
  };

  STAGE(0, 0);
  __syncthreads();

#pragma unroll 1
  for (int kk = 0; kk < 8; ++kk) {
    const int cur = kk & 1;
    if (kk < 7) STAGE(cur ^ 1, kk + 1);  // issue next K-tile loads (hidden)

#pragma unroll
    for (int ksub = 0; ksub < 2; ++ksub) {
      const int kc = ksub * 4 + (lane >> 4);  // logical 16B chunk 0..7
      bf16x8 af[4], bfr[4];
#pragma unroll
      for (int mi = 0; mi < 4; ++mi) {
        const int r = mrow + mi * 16;
        af[mi] = *(const bf16x8*)&sA[cur][r * 64 + ((kc ^ (r & 7)) << 3)];
      }
#pragma unroll
      for (int ni = 0; ni < 4; ++ni) {
        const int r = nrow + ni * 16;
        bfr[ni] = *(const bf16x8*)&sB[cur][r * 64 + ((kc ^ (r & 7)) << 3)];
      }
#pragma unroll
      for (int mi = 0; mi < 4; ++mi)
#pragma unroll
        for (int ni = 0; ni < 4; ++ni)
          acc[mi][ni] = __builtin_amdgcn_mfma_f32_16x16x32_bf16(af[mi], bfr[ni], acc[mi][ni], 0, 0, 0);
    }
    __syncthreads();  // drains vmcnt: next buffer ready; cur free for write
  }

  float* O = out + (size_t)c * NPOS + (size_t)i0 * NDIM + j0;
#pragma unroll
  for (int mi = 0; mi < 4; ++mi)
#pragma unroll
    for (int r = 0; r < 4; ++r) {
      const int m = wm * 64 + mi * 16 + (lane >> 4) * 4 + r;
#pragma unroll
      for (int ni = 0; ni < 4; ++ni) {
        const int n = wn * 64 + ni * 16 + (lane & 15);
        O[(size_t)m * NDIM + n] = acc[mi][ni][r];
      }
    }
}

// ---------------------------------------------------------------- launcher
extern "C" void kernel_launch(void* const* d_in, const int* in_sizes, int n_in,
                              void* d_out, int out_size, void* d_ws, size_t ws_size,
                              hipStream_t stream) {
  const float* z    = (const float*)d_in[0];
  const float* mask = (const float*)d_in[1];
  const float* wag  = (const float*)d_in[2];
  const float* bag  = (const float*)d_in[3];
  const float* wap  = (const float*)d_in[4];
  const float* bap  = (const float*)d_in[5];
  const float* wbg  = (const float*)d_in[6];
  const float* bbg  = (const float*)d_in[7];
  const float* wbp  = (const float*)d_in[8];
  const float* bbp  = (const float*)d_in[9];
  float* out = (float*)d_out;

  unsigned short* wbf  = (unsigned short*)d_ws;
  unsigned short* a_ws = (unsigned short*)((char*)d_ws + 131072);
  unsigned short* b_ws = (unsigned short*)((char*)d_ws + 131072 + (size_t)CH * NPOS * 2);

  conv_weights<<<dim3(256), dim3(256), 0, stream>>>(wag, wap, wbg, wbp, wbf);
  proj_fuse<<<dim3(NPOS / POSB, 2), dim3(256), 0, stream>>>(
      z, mask, wbf, bag, bap, bbg, bbp, a_ws, b_ws);
  tri_gemm<<<dim3(2048), dim3(256), 0, stream>>>(a_ws, b_ws, out);
}

// Round 4
// 374.094 us; speedup vs baseline: 1.1825x; 1.0235x over previous
//
#include <hip/hip_runtime.h>
#include <stdint.h>

// Triangle multiplicative update (outgoing), N=512, CZ=CH=128.
// Stage A (proj_fuse v4): grid (512,2); y picks pair (a|b). 256-thread
//   blocks, wave = channel quarter, gate+lin weights VGPR-resident and
//   PINNED via asm (v3's VGPR_Count=76 proved the compiler rematerialized
//   the loads in-loop; the pin makes remat impossible). T14 async staging:
//   z loads issued before compute, convert+ds_write after. cvt_pk_bf16
//   packing (1 op / 2 elems, same RNE) and rcp-based sigmoid.
// Stage B (tri_gemm, reverted to R1 structure): single-buffered LDS,
//   lb(256,3) -> 3 blocks/CU; R3's double-buffer@2 blocks measured ~10us
//   WORSE (wall-clock subtraction). c-locality XCD swizzle kept: all 16
//   tiles of channel c on one XCD -> A_c/B_c HBM-fetched once.

#define NDIM 512
#define CZ   128
#define CH   128
#define NPOS (NDIM * NDIM)  // 262144
#define NTILE 16            // position tiles per proj_fuse block
#define POSB  (NTILE * 32)  // 512 positions per block

typedef __attribute__((ext_vector_type(8))) __bf16 bf16x8;
typedef __attribute__((ext_vector_type(4))) float  f32x4;

__device__ __forceinline__ unsigned short f2bf(float f) {
  unsigned int u = __builtin_bit_cast(unsigned int, f);
  unsigned int r = (u + 0x7fffu + ((u >> 16) & 1u)) >> 16;  // RNE
  return (unsigned short)r;
}
// v_cvt_pk_bf16_f32: dst.lo = bf16(lo), dst.hi = bf16(hi); RNE — bit-equal
// to f2bf for normal inputs. 1 VALU op per 2 elements (vs ~3/elem manual).
__device__ __forceinline__ unsigned int cvt_pk_bf16(float lo, float hi) {
  unsigned int r;
  asm("v_cvt_pk_bf16_f32 %0, %1, %2" : "=v"(r) : "v"(lo), "v"(hi));
  return r;
}

// ---------------------------------------------------------------- kernel 0
// fp32 -> bf16 weights, layout [proj][c][k], proj: 0=ag,1=ap,2=bg,3=bp.
__global__ __launch_bounds__(256) void conv_weights(
    const float* __restrict__ wag, const float* __restrict__ wap,
    const float* __restrict__ wbg, const float* __restrict__ wbp,
    unsigned short* __restrict__ wbf) {
  int idx = blockIdx.x * 256 + threadIdx.x;  // 0..65535
  int proj = idx >> 14;
  int rem  = idx & 16383;
  const float* src = (proj == 0) ? wag : (proj == 1) ? wap : (proj == 2) ? wbg : wbp;
  wbf[idx] = f2bf(src[rem]);
}

// ---------------------------------------------------------------- kernel A
__global__ __launch_bounds__(256, 3) void proj_fuse(
    const float* __restrict__ z,            // [NPOS][CZ]
    const float* __restrict__ mask,         // [NPOS]
    const unsigned short* __restrict__ wbf, // [4][CH][CZ] bf16
    const float* __restrict__ bias_ag, const float* __restrict__ bias_ap,
    const float* __restrict__ bias_bg, const float* __restrict__ bias_bp,
    unsigned short* __restrict__ a_ws,      // [CH][NPOS] bf16
    unsigned short* __restrict__ b_ws) {
  __shared__ unsigned short zbuf[2][32 * 136];  // 2 x 8.7 KB, padded stride

  const int t    = threadIdx.x;
  const int lane = t & 63;
  const int w    = t >> 6;          // 0..3 = channel quarter
  const int pair = blockIdx.y;      // 0=a, 1=b
  const int base = blockIdx.x * POSB;

  const int ml    = lane & 15;
  const int q     = lane >> 4;
  const int koffl = q * 8;
  const int pg = pair * 2, pp = pg + 1;

  // ---- weights: gate + lin for 32 channels -> 64 VGPR, loaded ONCE.
  bf16x8 wg[4][2], wp[4][2];
#pragma unroll
  for (int ks = 0; ks < 4; ++ks)
#pragma unroll
    for (int ni = 0; ni < 2; ++ni) {
      const int c = w * 32 + ni * 16 + ml;
      wg[ks][ni] = *(const bf16x8*)&wbf[((size_t)pg * CH + c) * CZ + ks * 32 + koffl];
      wp[ks][ni] = *(const bf16x8*)&wbf[((size_t)pp * CH + c) * CZ + ks * 32 + koffl];
    }
  // PIN: asm-defined values cannot be rematerialized -> stays in registers.
#pragma unroll
  for (int ks = 0; ks < 4; ++ks)
#pragma unroll
    for (int ni = 0; ni < 2; ++ni) {
      asm volatile("" : "+v"(wg[ks][ni]));
      asm volatile("" : "+v"(wp[ks][ni]));
    }

  // ---- biases for this lane's channels
  const float* bgp = pair ? bias_bg : bias_ag;
  const float* bpp = pair ? bias_bp : bias_ap;
  float bg[2], bp[2];
#pragma unroll
  for (int ni = 0; ni < 2; ++ni) {
    bg[ni] = bgp[w * 32 + ni * 16 + ml];
    bp[ni] = bpp[w * 32 + ni * 16 + ml];
  }
  unsigned short* plane = pair ? b_ws : a_ws;

  // ---- T14 split staging: load early (regs), convert+write late.
  float4 stg[4];
  auto STAGE_LOAD = [&](int tt) {
    const int m0s = base + tt * 32;
#pragma unroll
    for (int it = 0; it < 4; ++it) {
      const int id  = it * 256 + t;   // 0..1023
      stg[it] = *(const float4*)(z + (size_t)(m0s + (id >> 5)) * CZ + (id & 31) * 4);
    }
  };
  auto STAGE_WRITE = [&](int b) {
#pragma unroll
    for (int it = 0; it < 4; ++it) {
      const int id = it * 256 + t;
      *(uint2*)&zbuf[b][(id >> 5) * 136 + (id & 31) * 4] =
          make_uint2(cvt_pk_bf16(stg[it].x, stg[it].y),
                     cvt_pk_bf16(stg[it].z, stg[it].w));
    }
  };

  STAGE_LOAD(0);
  STAGE_WRITE(0);
  __syncthreads();

#pragma unroll 1
  for (int tt = 0; tt < NTILE; ++tt) {
    const int m0 = base + tt * 32;
    const int cb = tt & 1;
    if (tt + 1 < NTILE) STAGE_LOAD(tt + 1);  // issue loads; hide under compute

    // ---- MFMA: gate+lin over [32 pos][32 ch]
    f32x4 ag_[2][2], ap_[2][2];
#pragma unroll
    for (int mi = 0; mi < 2; ++mi)
#pragma unroll
      for (int ni = 0; ni < 2; ++ni) {
        ag_[mi][ni] = (f32x4){0.f, 0.f, 0.f, 0.f};
        ap_[mi][ni] = (f32x4){0.f, 0.f, 0.f, 0.f};
      }

#pragma unroll
    for (int ks = 0; ks < 4; ++ks) {
      bf16x8 af0 = *(const bf16x8*)&zbuf[cb][(ml)      * 136 + ks * 32 + koffl];
      bf16x8 af1 = *(const bf16x8*)&zbuf[cb][(ml + 16) * 136 + ks * 32 + koffl];
#pragma unroll
      for (int ni = 0; ni < 2; ++ni) {
        ag_[0][ni] = __builtin_amdgcn_mfma_f32_16x16x32_bf16(af0, wg[ks][ni], ag_[0][ni], 0, 0, 0);
        ag_[1][ni] = __builtin_amdgcn_mfma_f32_16x16x32_bf16(af1, wg[ks][ni], ag_[1][ni], 0, 0, 0);
        ap_[0][ni] = __builtin_amdgcn_mfma_f32_16x16x32_bf16(af0, wp[ks][ni], ap_[0][ni], 0, 0, 0);
        ap_[1][ni] = __builtin_amdgcn_mfma_f32_16x16x32_bf16(af1, wp[ks][ni], ap_[1][ni], 0, 0, 0);
      }
    }

    // ---- in-register epilogue: out = mask*sigmoid(g+bg)*(p+bp)
    // C-layout (validated): channel = ni*16+ml, pos = mi*16+q*4+r
#pragma unroll
    for (int mi = 0; mi < 2; ++mi) {
      const int pos0 = mi * 16 + q * 4;
      const float4 mv = *(const float4*)(mask + m0 + pos0);
      const float mr[4] = {mv.x, mv.y, mv.z, mv.w};
#pragma unroll
      for (int ni = 0; ni < 2; ++ni) {
        const int c = w * 32 + ni * 16 + ml;
        float v[4];
#pragma unroll
        for (int r = 0; r < 4; ++r) {
          const float g = ag_[mi][ni][r] + bg[ni];
          const float p = ap_[mi][ni][r] + bp[ni];
          const float s = __builtin_amdgcn_rcpf(1.0f + __expf(-g));
          v[r] = mr[r] * s * p;
        }
        *(uint2*)(plane + (size_t)c * NPOS + m0 + pos0) =
            make_uint2(cvt_pk_bf16(v[0], v[1]), cvt_pk_bf16(v[2], v[3]));
      }
    }

    if (tt + 1 < NTILE) STAGE_WRITE(cb ^ 1);  // vmcnt waits land here
    __syncthreads();
  }
}

// ---------------------------------------------------------------- kernel B
// Per-channel GEMM out[c] = A_c * B_c^T, bf16 [512][512].
// 128x128 tile, BK=64, single-buffered LDS (3 blocks/CU; measured better
// than dbuf@2), global_load_lds width-16, XOR-swizzled chunks, c-locality
// XCD swizzle.
__global__ __launch_bounds__(256, 3) void tri_gemm(
    const unsigned short* __restrict__ a_ws,
    const unsigned short* __restrict__ b_ws,
    float* __restrict__ out) {
  __shared__ unsigned short sA[128 * 64];
  __shared__ unsigned short sB[128 * 64];

  const int t = threadIdx.x, lane = t & 63, wave = t >> 6;
  const int wm = wave >> 1, wn = wave & 1;

  const int L    = blockIdx.x;     // 0..2047
  const int xcd  = L & 7;
  const int slot = L >> 3;         // 0..255
  const int c    = xcd * 16 + (slot >> 4);
  const int tile = slot & 15;      // 16 tiles of channel c, schedule-adjacent
  const int ti   = tile >> 2, tj = tile & 3;
  const int i0 = ti * 128, j0 = tj * 128;

  const unsigned short* Ap = a_ws + (size_t)c * NPOS + (size_t)i0 * NDIM;
  const unsigned short* Bp = b_ws + (size_t)c * NPOS + (size_t)j0 * NDIM;

  f32x4 acc[4][4];
#pragma unroll
  for (int mi = 0; mi < 4; ++mi)
#pragma unroll
    for (int ni = 0; ni < 4; ++ni) acc[mi][ni] = (f32x4){0.f, 0.f, 0.f, 0.f};

  const int srow8  = t >> 3;  // row within a 32-row staging group
  const int schunk = t & 7;   // physical 16B chunk within row
  const int mrow = wm * 64 + (lane & 15);
  const int nrow = wn * 64 + (lane & 15);

  for (int kk = 0; kk < 8; ++kk) {
    const int k0 = kk * 64;  // shorts
#pragma unroll
    for (int i = 0; i < 4; ++i) {
      const int row = i * 32 + srow8;
      const int kcs = schunk ^ (row & 7);  // swizzled source chunk
      __builtin_amdgcn_global_load_lds(
          (const __attribute__((address_space(1))) unsigned int*)(Ap + (size_t)row * NDIM + k0 + kcs * 8),
          (__attribute__((address_space(3))) unsigned int*)&sA[(i * 256 + t) * 8], 16, 0, 0);
      __builtin_amdgcn_global_load_lds(
          (const __attribute__((address_space(1))) unsigned int*)(Bp + (size_t)row * NDIM + k0 + kcs * 8),
          (__attribute__((address_space(3))) unsigned int*)&sB[(i * 256 + t) * 8], 16, 0, 0);
    }
    __syncthreads();

#pragma unroll
    for (int ksub = 0; ksub < 2; ++ksub) {
      const int kc = ksub * 4 + (lane >> 4);  // logical 16B chunk 0..7
      bf16x8 af[4], bfr[4];
#pragma unroll
      for (int mi = 0; mi < 4; ++mi) {
        const int r = mrow + mi * 16;
        af[mi] = *(const bf16x8*)&sA[r * 64 + ((kc ^ (r & 7)) << 3)];
      }
#pragma unroll
      for (int ni = 0; ni < 4; ++ni) {
        const int r = nrow + ni * 16;
        bfr[ni] = *(const bf16x8*)&sB[r * 64 + ((kc ^ (r & 7)) << 3)];
      }
#pragma unroll
      for (int mi = 0; mi < 4; ++mi)
#pragma unroll
        for (int ni = 0; ni < 4; ++ni)
          acc[mi][ni] = __builtin_amdgcn_mfma_f32_16x16x32_bf16(af[mi], bfr[ni], acc[mi][ni], 0, 0, 0);
    }
    __syncthreads();
  }

  float* O = out + (size_t)c * NPOS + (size_t)i0 * NDIM + j0;
#pragma unroll
  for (int mi = 0; mi < 4; ++mi)
#pragma unroll
    for (int r = 0; r < 4; ++r) {
      const int m = wm * 64 + mi * 16 + (lane >> 4) * 4 + r;
#pragma unroll
      for (int ni = 0; ni < 4; ++ni) {
        const int n = wn * 64 + ni * 16 + (lane & 15);
        O[(size_t)m * NDIM + n] = acc[mi][ni][r];
      }
    }
}

// ---------------------------------------------------------------- launcher
extern "C" void kernel_launch(void* const* d_in, const int* in_sizes, int n_in,
                              void* d_out, int out_size, void* d_ws, size_t ws_size,
                              hipStream_t stream) {
  const float* z    = (const float*)d_in[0];
  const float* mask = (const float*)d_in[1];
  const float* wag  = (const float*)d_in[2];
  const float* bag  = (const float*)d_in[3];
  const float* wap  = (const float*)d_in[4];
  const float* bap  = (const float*)d_in[5];
  const float* wbg  = (const float*)d_in[6];
  const float* bbg  = (const float*)d_in[7];
  const float* wbp  = (const float*)d_in[8];
  const float* bbp  = (const float*)d_in[9];
  float* out = (float*)d_out;

  unsigned short* wbf  = (unsigned short*)d_ws;
  unsigned short* a_ws = (unsigned short*)((char*)d_ws + 131072);
  unsigned short* b_ws = (unsigned short*)((char*)d_ws + 131072 + (size_t)CH * NPOS * 2);

  conv_weights<<<dim3(256), dim3(256), 0, stream>>>(wag, wap, wbg, wbp, wbf);
  proj_fuse<<<dim3(NPOS / POSB, 2), dim3(256), 0, stream>>>(
      z, mask, wbf, bag, bap, bbg, bbp, a_ws, b_ws);
  tri_gemm<<<dim3(2048), dim3(256), 0, stream>>>(a_ws, b_ws, out);
}